// Round 1
// baseline (259.322 us; speedup 1.0000x reference)
//
#include <hip/hip_runtime.h>

typedef __attribute__((ext_vector_type(8))) short short8;
typedef __attribute__((ext_vector_type(4))) float f32x4;

__device__ __forceinline__ unsigned short f2bf(float f) {
  unsigned int u = __float_as_uint(f);
  u += 0x7fffu + ((u >> 16) & 1u);
  return (unsigned short)(u >> 16);
}

__device__ __forceinline__ float bf2f(unsigned short s) {
  unsigned int u = ((unsigned int)s) << 16;
  return __uint_as_float(u);
}

// Transpose+convert the 6 weight matrices fp32 [k][n] -> bf16 [n][k].
// Layout in ws: [WuT, WrT, WhT, UuT, UrT, UhT], each 256*256 ushort.
__global__ __launch_bounds__(256) void wprep(
    const float* __restrict__ Wu, const float* __restrict__ Wr, const float* __restrict__ Wh,
    const float* __restrict__ Uu, const float* __restrict__ Ur, const float* __restrict__ Uh,
    unsigned short* __restrict__ wt) {
  int idx = blockIdx.x * 256 + threadIdx.x;   // 0 .. 6*65536
  int w   = idx >> 16;
  int rem = idx & 65535;
  int n = rem >> 8, k = rem & 255;
  const float* src = (w == 0) ? Wu : (w == 1) ? Wr : (w == 2) ? Wh
                   : (w == 3) ? Uu : (w == 4) ? Ur : Uh;
  wt[idx] = f2bf(src[k * 256 + n]);
}

// Fused AUGRU: per block BM=64 rows, full D=256 cols.
// 4 waves, wave w owns cols [64w, 64w+64), processed in 4 chunks of 16 cols.
// acc_u = x@Wu + h@Uu ; acc_r = x@Wr + h@Ur ; acc_xh = x@Wh ; acc_hh = h@Uh
__global__ __launch_bounds__(256, 2) void augru_main(
    const float* __restrict__ x, const float* __restrict__ h1,
    const float* __restrict__ a, const unsigned short* __restrict__ wt,
    const float* __restrict__ bu, const float* __restrict__ br,
    const float* __restrict__ bh, float* __restrict__ out) {
  __shared__ unsigned short lds[2][64 * 256];   // [0]=x tile, [1]=h tile, bf16, XOR-swizzled

  const int tid = threadIdx.x;
  const int l   = tid & 63;
  const int wid = tid >> 6;            // 0..3 -> column group
  const int fr  = l & 15;              // fragment row (A) / col (B,C)
  const int fq  = l >> 4;              // quarter: k-chunk for A/B, row-group for C
  const long rowbase = (long)blockIdx.x * 64;

  // ---- stage x and h tiles to LDS as bf16, swizzled: byte ^= (row&7)<<4 ----
  for (int s = 0; s < 2; ++s) {
    const float* src = (s == 0 ? x : h1) + rowbase * 256;
    char* dstb = (char*)(&lds[s][0]);
#pragma unroll
    for (int i = 0; i < 16; ++i) {
      int f   = i * 256 + tid;          // float4 index within 64x256 tile
      int row = f >> 6;                 // 64 float4 per row
      int kq  = f & 63;
      float4 v = ((const float4*)src)[f];
      ushort4 b;
      b.x = f2bf(v.x); b.y = f2bf(v.y); b.z = f2bf(v.z); b.w = f2bf(v.w);
      int off = (kq * 8) ^ ((row & 7) << 4);
      *(ushort4*)(dstb + (row << 9) + off) = b;
    }
  }
  __syncthreads();

  const int swz = (fr & 7) << 4;

#define GEMM_PASS(PIDX, ACCC)                                                     \
  {                                                                               \
    const char* lA = (const char*)(&lds[PIDX][0]);                                \
    const unsigned short* wb = wt + (PIDX) * 3 * 65536 + (nbase + fr) * 256 + fq * 8; \
    _Pragma("unroll")                                                             \
    for (int ks = 0; ks < 8; ++ks) {                                              \
      const int ka = ((ks << 6) + (fq << 4)) ^ swz;                               \
      short8 va0 = *(const short8*)(lA +     0 + (fr << 9) + ka);                 \
      short8 va1 = *(const short8*)(lA +  8192 + (fr << 9) + ka);                 \
      short8 va2 = *(const short8*)(lA + 16384 + (fr << 9) + ka);                 \
      short8 va3 = *(const short8*)(lA + 24576 + (fr << 9) + ka);                 \
      short8 vb0 = *(const short8*)(wb + (ks << 5));                              \
      short8 vb1 = *(const short8*)(wb + 65536 + (ks << 5));                      \
      short8 vb2 = *(const short8*)(wb + 131072 + (ks << 5));                     \
      accU[0] = __builtin_amdgcn_mfma_f32_16x16x32_bf16(va0, vb0, accU[0], 0, 0, 0); \
      accU[1] = __builtin_amdgcn_mfma_f32_16x16x32_bf16(va1, vb0, accU[1], 0, 0, 0); \
      accU[2] = __builtin_amdgcn_mfma_f32_16x16x32_bf16(va2, vb0, accU[2], 0, 0, 0); \
      accU[3] = __builtin_amdgcn_mfma_f32_16x16x32_bf16(va3, vb0, accU[3], 0, 0, 0); \
      accR[0] = __builtin_amdgcn_mfma_f32_16x16x32_bf16(va0, vb1, accR[0], 0, 0, 0); \
      accR[1] = __builtin_amdgcn_mfma_f32_16x16x32_bf16(va1, vb1, accR[1], 0, 0, 0); \
      accR[2] = __builtin_amdgcn_mfma_f32_16x16x32_bf16(va2, vb1, accR[2], 0, 0, 0); \
      accR[3] = __builtin_amdgcn_mfma_f32_16x16x32_bf16(va3, vb1, accR[3], 0, 0, 0); \
      ACCC[0] = __builtin_amdgcn_mfma_f32_16x16x32_bf16(va0, vb2, ACCC[0], 0, 0, 0); \
      ACCC[1] = __builtin_amdgcn_mfma_f32_16x16x32_bf16(va1, vb2, ACCC[1], 0, 0, 0); \
      ACCC[2] = __builtin_amdgcn_mfma_f32_16x16x32_bf16(va2, vb2, ACCC[2], 0, 0, 0); \
      ACCC[3] = __builtin_amdgcn_mfma_f32_16x16x32_bf16(va3, vb2, ACCC[3], 0, 0, 0); \
    }                                                                             \
  }

  for (int c = 0; c < 4; ++c) {
    const int nbase = wid * 64 + c * 16;
    f32x4 accU[4] = {0.f, 0.f, 0.f, 0.f};
    f32x4 accR[4] = {0.f, 0.f, 0.f, 0.f};
    f32x4 accXH[4] = {0.f, 0.f, 0.f, 0.f};
    f32x4 accHH[4] = {0.f, 0.f, 0.f, 0.f};

    GEMM_PASS(0, accXH)   // x @ {Wu, Wr, Wh}
    GEMM_PASS(1, accHH)   // h @ {Uu, Ur, Uh}

    // ---- epilogue: per-element gates + blend ----
    const int n = nbase + fr;
    const float vbu = bu[n], vbr = br[n], vbh = bh[n];
#pragma unroll
    for (int m = 0; m < 4; ++m) {
#pragma unroll
      for (int j = 0; j < 4; ++j) {
        const int row = m * 16 + fq * 4 + j;     // C layout: col=lane&15, row=(lane>>4)*4+reg
        const long grow = rowbase + row;
        const float av = a[grow];
        const float pu = accU[m][j] + vbu;
        const float pr = accR[m][j] + vbr;
        const float u = 1.f / (1.f + __expf(-pu));
        const float r = 1.f / (1.f + __expf(-pr));
        const float cc = accXH[m][j] + r * accHH[m][j] + vbh;
        const float th = 2.f / (1.f + __expf(-2.f * cc)) - 1.f;
        const float uh = av * u;
        const long idx = grow * 256 + n;
        const float h1v = h1[idx];
        out[idx] = (1.f - uh) * h1v + uh * th;
      }
    }
  }
#undef GEMM_PASS
}

extern "C" void kernel_launch(void* const* d_in, const int* in_sizes, int n_in,
                              void* d_out, int out_size, void* d_ws, size_t ws_size,
                              hipStream_t stream) {
  const float* x  = (const float*)d_in[0];
  const float* h1 = (const float*)d_in[1];
  const float* a  = (const float*)d_in[2];
  const float* Wu = (const float*)d_in[3];
  const float* Uu = (const float*)d_in[4];
  const float* bu = (const float*)d_in[5];
  const float* Wr = (const float*)d_in[6];
  const float* Ur = (const float*)d_in[7];
  const float* br = (const float*)d_in[8];
  const float* Wh = (const float*)d_in[9];
  const float* Uh = (const float*)d_in[10];
  const float* bh = (const float*)d_in[11];
  unsigned short* wt = (unsigned short*)d_ws;   // 6*65536 bf16 = 768 KB

  wprep<<<1536, 256, 0, stream>>>(Wu, Wr, Wh, Uu, Ur, Uh, wt);

  const int rows = in_sizes[0] / 256;           // 65536
  augru_main<<<rows / 64, 256, 0, stream>>>(x, h1, a, wt, bu, br, bh, (float*)d_out);
}

// Round 2
// 246.983 us; speedup vs baseline: 1.0500x; 1.0500x over previous
//
#include <hip/hip_runtime.h>

typedef __attribute__((ext_vector_type(8))) short short8;
typedef __attribute__((ext_vector_type(16))) float f32x16;

__device__ __forceinline__ unsigned short f2bf(float f) {
  unsigned int u = __float_as_uint(f);
  u += 0x7fffu + ((u >> 16) & 1u);
  return (unsigned short)(u >> 16);
}

__device__ __forceinline__ float bf2f(unsigned short s) {
  unsigned int u = ((unsigned int)s) << 16;
  return __uint_as_float(u);
}

// Transpose+convert the 6 weight matrices fp32 [k][n] -> bf16 [n][k].
// Layout in ws: [WuT, WrT, WhT, UuT, UrT, UhT], each 256*256 ushort.
__global__ __launch_bounds__(256) void wprep(
    const float* __restrict__ Wu, const float* __restrict__ Wr, const float* __restrict__ Wh,
    const float* __restrict__ Uu, const float* __restrict__ Ur, const float* __restrict__ Uh,
    unsigned short* __restrict__ wt) {
  int idx = blockIdx.x * 256 + threadIdx.x;   // 0 .. 6*65536
  int w   = idx >> 16;
  int rem = idx & 65535;
  int n = rem >> 8, k = rem & 255;
  const float* src = (w == 0) ? Wu : (w == 1) ? Wr : (w == 2) ? Wh
                   : (w == 3) ? Uu : (w == 4) ? Ur : Uh;
  wt[idx] = f2bf(src[k * 256 + n]);
}

// Fused AUGRU. Block = 512 thr (8 waves), tile 64 rows x 256 cols.
// Wave (wrow,wcol): rows wrow*32..+32, cols wcol*64..+64, two 32-col chunks.
// mfma_f32_32x32x16_bf16; acc per chunk: u, r, x@Wh, h@Uh (4 x f32x16).
__global__ __launch_bounds__(512, 4) void augru_main(
    const float* __restrict__ x, const float* __restrict__ h1,
    const float* __restrict__ a, const unsigned short* __restrict__ wt,
    const float* __restrict__ bu, const float* __restrict__ br,
    const float* __restrict__ bh, float* __restrict__ out) {
  __shared__ unsigned short lds[2][64 * 256];   // [0]=x tile, [1]=h tile, bf16, swizzled
  __shared__ float a_s[64];

  const int tid  = threadIdx.x;
  const int l    = tid & 63;
  const int wid  = tid >> 6;           // 0..7
  const int wrow = wid >> 2;           // 0..1
  const int wcol = wid & 3;            // 0..3
  const int fr   = l & 31;             // A row / B,C col within 32x32 tile
  const int fq   = l >> 5;             // k half (A/B); row offset +4 (C)
  const long rowbase = (long)blockIdx.x * 64;

  // ---- stage x and h tiles to LDS as bf16, swizzled: byte ^= (row&7)<<4 ----
  for (int s = 0; s < 2; ++s) {
    const float* src = (s == 0 ? x : h1) + rowbase * 256;
    char* dstb = (char*)(&lds[s][0]);
#pragma unroll
    for (int i = 0; i < 8; ++i) {
      int f   = i * 512 + tid;          // float4 index within 64x256 tile
      int row = f >> 6;                 // 64 float4 per row
      int kq  = f & 63;
      float4 v = ((const float4*)src)[f];
      ushort4 b;
      b.x = f2bf(v.x); b.y = f2bf(v.y); b.z = f2bf(v.z); b.w = f2bf(v.w);
      int off = (kq * 8) ^ ((row & 7) << 4);
      *(ushort4*)(dstb + (row << 9) + off) = b;
    }
  }
  if (tid < 64) a_s[tid] = a[rowbase + tid];
  __syncthreads();

  const char* lA = (const char*)(&lds[0][0]);   // x tile
  const char* lH = (const char*)(&lds[1][0]);   // h tile

  const int arow  = wrow * 32 + fr;
  const int aswz  = (arow & 7) << 4;
  const int abase = arow << 9;

  for (int ch = 0; ch < 2; ++ch) {
    const int nbase = wcol * 64 + ch * 32;
    const int n = nbase + fr;
    f32x16 accU = {};
    f32x16 accR = {};
    f32x16 accXH = {};
    f32x16 accHH = {};

    // pass 0: x @ {Wu, Wr, Wh}
    {
      const unsigned short* wb = wt + (long)n * 256 + fq * 8;
#pragma unroll 2
      for (int ks = 0; ks < 16; ++ks) {
        short8 va  = *(const short8*)(lA + abase + (((ks << 5) + (fq << 4)) ^ aswz));
        short8 vb0 = *(const short8*)(wb + (ks << 4));
        short8 vb1 = *(const short8*)(wb + 65536 + (ks << 4));
        short8 vb2 = *(const short8*)(wb + 131072 + (ks << 4));
        accU  = __builtin_amdgcn_mfma_f32_32x32x16_bf16(va, vb0, accU, 0, 0, 0);
        accR  = __builtin_amdgcn_mfma_f32_32x32x16_bf16(va, vb1, accR, 0, 0, 0);
        accXH = __builtin_amdgcn_mfma_f32_32x32x16_bf16(va, vb2, accXH, 0, 0, 0);
      }
    }
    // pass 1: h @ {Uu, Ur, Uh}
    {
      const unsigned short* wb = wt + 3 * 65536 + (long)n * 256 + fq * 8;
#pragma unroll 2
      for (int ks = 0; ks < 16; ++ks) {
        short8 va  = *(const short8*)(lH + abase + (((ks << 5) + (fq << 4)) ^ aswz));
        short8 vb0 = *(const short8*)(wb + (ks << 4));
        short8 vb1 = *(const short8*)(wb + 65536 + (ks << 4));
        short8 vb2 = *(const short8*)(wb + 131072 + (ks << 4));
        accU  = __builtin_amdgcn_mfma_f32_32x32x16_bf16(va, vb0, accU, 0, 0, 0);
        accR  = __builtin_amdgcn_mfma_f32_32x32x16_bf16(va, vb1, accR, 0, 0, 0);
        accHH = __builtin_amdgcn_mfma_f32_32x32x16_bf16(va, vb2, accHH, 0, 0, 0);
      }
    }

    // ---- epilogue: gates + blend; stores cover full 128B lines ----
    const float vbu = bu[n], vbr = br[n], vbh = bh[n];
#pragma unroll
    for (int g = 0; g < 4; ++g) {
#pragma unroll
      for (int j = 0; j < 4; ++j) {
        const int reg = g * 4 + j;
        const int rl  = wrow * 32 + fq * 4 + j + g * 8;  // local row (C layout)
        const long grow = rowbase + rl;
        const float av = a_s[rl];
        const float pu = accU[reg] + vbu;
        const float pr = accR[reg] + vbr;
        const float u = 1.f / (1.f + __expf(-pu));
        const float r = 1.f / (1.f + __expf(-pr));
        const float cc = accXH[reg] + r * accHH[reg] + vbh;
        const float th = 2.f / (1.f + __expf(-2.f * cc)) - 1.f;
        const float uh = av * u;
        // h1 from LDS (bf16)
        const int hb = (rl << 9) + ((((n >> 2) << 3)) ^ ((rl & 7) << 4)) + ((n & 3) << 1);
        const float h1v = bf2f(*(const unsigned short*)(lH + hb));
        out[grow * 256 + n] = (1.f - uh) * h1v + uh * th;
      }
    }
  }
}

extern "C" void kernel_launch(void* const* d_in, const int* in_sizes, int n_in,
                              void* d_out, int out_size, void* d_ws, size_t ws_size,
                              hipStream_t stream) {
  const float* x  = (const float*)d_in[0];
  const float* h1 = (const float*)d_in[1];
  const float* a  = (const float*)d_in[2];
  const float* Wu = (const float*)d_in[3];
  const float* Uu = (const float*)d_in[4];
  const float* bu = (const float*)d_in[5];
  const float* Wr = (const float*)d_in[6];
  const float* Ur = (const float*)d_in[7];
  const float* br = (const float*)d_in[8];
  const float* Wh = (const float*)d_in[9];
  const float* Uh = (const float*)d_in[10];
  const float* bh = (const float*)d_in[11];
  unsigned short* wt = (unsigned short*)d_ws;   // 6*65536 bf16 = 768 KB

  wprep<<<1536, 256, 0, stream>>>(Wu, Wr, Wh, Uu, Ur, Uh, wt);

  const int rows = in_sizes[0] / 256;           // 65536
  augru_main<<<rows / 64, 512, 0, stream>>>(x, h1, a, wt, bu, br, bh, (float*)d_out);
}

// Round 3
// 110.965 us; speedup vs baseline: 2.3370x; 2.2258x over previous
//
#include <hip/hip_runtime.h>

typedef __attribute__((ext_vector_type(8))) short short8;
typedef __attribute__((ext_vector_type(16))) float f32x16;

#define MFMA32 __builtin_amdgcn_mfma_f32_32x32x16_bf16

__device__ __forceinline__ unsigned short f2bf(float f) {
  unsigned int u = __float_as_uint(f);
  u += 0x7fffu + ((u >> 16) & 1u);
  return (unsigned short)(u >> 16);
}

__device__ __forceinline__ float bf2f(unsigned short s) {
  unsigned int u = ((unsigned int)s) << 16;
  return __uint_as_float(u);
}

__device__ __forceinline__ void gl_lds16(const void* g, void* l) {
  __builtin_amdgcn_global_load_lds(
      (const __attribute__((address_space(1))) unsigned int*)g,
      (__attribute__((address_space(3))) unsigned int*)l, 16, 0, 0);
}

// Pre-pack the 6 weight matrices fp32 [k][n] -> bf16 MFMA-fragment order:
// wt[(((s*6 + g)*8 + c)*64 + l)*8 + j] = G_g[k][n]
//   with k = s*16 + (l>>5)*8 + j, n = c*32 + (l&31)
// so each K=16 slab is a contiguous 48 KB block, fragment-ordered.
__global__ __launch_bounds__(256) void wprep(
    const float* __restrict__ Wu, const float* __restrict__ Wr, const float* __restrict__ Wh,
    const float* __restrict__ Uu, const float* __restrict__ Ur, const float* __restrict__ Uh,
    unsigned short* __restrict__ wt) {
  int idx = blockIdx.x * 256 + threadIdx.x;   // 0 .. 6*65536-1
  int j = idx & 7;
  int l = (idx >> 3) & 63;
  int c = (idx >> 9) & 7;
  int sg = idx >> 12;
  int g = sg % 6;
  int s = sg / 6;
  int k = s * 16 + (l >> 5) * 8 + j;
  int n = c * 32 + (l & 31);
  const float* src = (g == 0) ? Wu : (g == 1) ? Wr : (g == 2) ? Wh
                   : (g == 3) ? Uu : (g == 4) ? Ur : Uh;
  wt[idx] = f2bf(src[k * 256 + n]);
}

// Fused AUGRU. Block = 512 thr (8 waves), tile 64 rows x 256 cols.
// Wave w owns cols [32w, 32w+32), all 64 rows (2 m-frags), mfma 32x32x16.
// Weights streamed K-slab(16) at a time into LDS via global_load_lds, dbuf.
__global__ __launch_bounds__(512, 2) void augru_main(
    const float* __restrict__ x, const float* __restrict__ h1,
    const float* __restrict__ a, const unsigned short* __restrict__ wt,
    const float* __restrict__ bu, const float* __restrict__ br,
    const float* __restrict__ bh, float* __restrict__ out) {
  extern __shared__ char smem[];
  char* w0 = smem;                  // 49152 B  weight slab buf 0
  char* w1 = smem + 49152;          // 49152 B  weight slab buf 1
  char* lX = smem + 98304;          // 32768 B  x tile bf16, swizzled
  char* lH = smem + 131072;         // 32768 B  h tile bf16, swizzled

  const int tid = threadIdx.x;
  const int l   = tid & 63;
  const int wid = tid >> 6;          // 0..7 -> 32-col chunk
  const int fr  = l & 31;            // row (A) / col (B,C)
  const int fq  = l >> 5;            // k-half (A/B) / row+4 group (C)
  const long rowbase = (long)blockIdx.x * 64;
  const int aswz = (fr & 7) << 4;

  // one K=16 slab = 48 KB; 512 thr x 16 B x 6 rounds
#define STAGE(DST, S)                                                      \
  {                                                                        \
    const char* gsrc = (const char*)wt + (S) * 49152 + tid * 16;           \
    _Pragma("unroll")                                                      \
    for (int r = 0; r < 6; ++r)                                            \
      gl_lds16(gsrc + r * 8192, (DST) + r * 8192 + tid * 16);              \
  }

  // ---- issue weight slab 0 DMA, then stage x/h tiles (bf16, swizzled) ----
  STAGE(w0, 0)
  for (int ss = 0; ss < 2; ++ss) {
    const float* src = (ss == 0 ? x : h1) + rowbase * 256;
    char* dstb = (ss == 0 ? lX : lH);
#pragma unroll
    for (int i = 0; i < 8; ++i) {
      int f   = i * 512 + tid;        // float4 index within 64x256 tile
      int row = f >> 6;
      int kq  = f & 63;
      float4 v = ((const float4*)src)[f];
      ushort4 b;
      b.x = f2bf(v.x); b.y = f2bf(v.y); b.z = f2bf(v.z); b.w = f2bf(v.w);
      *(ushort4*)(dstb + (row << 9) + ((kq * 8) ^ ((row & 7) << 4))) = b;
    }
  }
  __syncthreads();   // drains STAGE(w0) DMA + x/h ds_writes

  f32x16 accU0 = {}, accU1 = {};
  f32x16 accR0 = {}, accR1 = {};
  f32x16 accXH0 = {}, accXH1 = {};
  f32x16 accHH0 = {}, accHH1 = {};

#define COMPUTE(WBUF, S)                                                   \
  {                                                                        \
    const int koff = ((S) * 32 + (fq << 4)) ^ aswz;                        \
    short8 ax0 = *(const short8*)(lX + (fr << 9) + koff);                  \
    short8 ax1 = *(const short8*)(lX + ((fr + 32) << 9) + koff);           \
    short8 ah0 = *(const short8*)(lH + (fr << 9) + koff);                  \
    short8 ah1 = *(const short8*)(lH + ((fr + 32) << 9) + koff);           \
    const char* wb = (WBUF) + wid * 1024 + l * 16;                         \
    short8 b0 = *(const short8*)(wb);                                      \
    short8 b1 = *(const short8*)(wb + 8192);                               \
    short8 b2 = *(const short8*)(wb + 16384);                              \
    short8 b3 = *(const short8*)(wb + 24576);                              \
    short8 b4 = *(const short8*)(wb + 32768);                              \
    short8 b5 = *(const short8*)(wb + 40960);                              \
    accU0  = MFMA32(ax0, b0, accU0, 0, 0, 0);                              \
    accU1  = MFMA32(ax1, b0, accU1, 0, 0, 0);                              \
    accR0  = MFMA32(ax0, b1, accR0, 0, 0, 0);                              \
    accR1  = MFMA32(ax1, b1, accR1, 0, 0, 0);                              \
    accXH0 = MFMA32(ax0, b2, accXH0, 0, 0, 0);                             \
    accXH1 = MFMA32(ax1, b2, accXH1, 0, 0, 0);                             \
    accU0  = MFMA32(ah0, b3, accU0, 0, 0, 0);                              \
    accU1  = MFMA32(ah1, b3, accU1, 0, 0, 0);                              \
    accR0  = MFMA32(ah0, b4, accR0, 0, 0, 0);                              \
    accR1  = MFMA32(ah1, b4, accR1, 0, 0, 0);                              \
    accHH0 = MFMA32(ah0, b5, accHH0, 0, 0, 0);                             \
    accHH1 = MFMA32(ah1, b5, accHH1, 0, 0, 0);                             \
  }

  for (int s = 0; s < 16; s += 2) {
    if (s + 1 < 16) STAGE(w1, s + 1)
    COMPUTE(w0, s)
    __syncthreads();                 // drains STAGE(w1); w0 free to overwrite
    if (s + 2 < 16) STAGE(w0, s + 2)
    COMPUTE(w1, s + 1)
    __syncthreads();                 // drains STAGE(w0); w1 free to overwrite
  }

  // ---- epilogue: gates + blend; full-128B-line stores ----
  const int n = wid * 32 + fr;
  const float vbu = bu[n], vbr = br[n], vbh = bh[n];

#define EPI(ACCU, ACCR, ACCXH, ACCHH, MBASE)                               \
  _Pragma("unroll")                                                        \
  for (int g8 = 0; g8 < 4; ++g8) {                                         \
    _Pragma("unroll")                                                      \
    for (int j = 0; j < 4; ++j) {                                          \
      const int reg = g8 * 4 + j;                                          \
      const int rl  = (MBASE) + g8 * 8 + fq * 4 + j;                       \
      const long grow = rowbase + rl;                                      \
      const float av = a[grow];                                            \
      const float pu = ACCU[reg] + vbu;                                    \
      const float pr = ACCR[reg] + vbr;                                    \
      const float uu = 1.f / (1.f + __expf(-pu));                          \
      const float rr = 1.f / (1.f + __expf(-pr));                          \
      const float cc = ACCXH[reg] + rr * ACCHH[reg] + vbh;                 \
      const float th = 2.f / (1.f + __expf(-2.f * cc)) - 1.f;              \
      const float uh = av * uu;                                            \
      const int hb = (rl << 9) + ((((n >> 2) << 3)) ^ ((rl & 7) << 4)) + ((n & 3) << 1); \
      const float h1v = bf2f(*(const unsigned short*)(lH + hb));           \
      out[grow * 256 + n] = (1.f - uh) * h1v + uh * th;                    \
    }                                                                      \
  }

  EPI(accU0, accR0, accXH0, accHH0, 0)
  EPI(accU1, accR1, accXH1, accHH1, 32)
#undef EPI
#undef COMPUTE
#undef STAGE
}

extern "C" void kernel_launch(void* const* d_in, const int* in_sizes, int n_in,
                              void* d_out, int out_size, void* d_ws, size_t ws_size,
                              hipStream_t stream) {
  const float* x  = (const float*)d_in[0];
  const float* h1 = (const float*)d_in[1];
  const float* a  = (const float*)d_in[2];
  const float* Wu = (const float*)d_in[3];
  const float* Uu = (const float*)d_in[4];
  const float* bu = (const float*)d_in[5];
  const float* Wr = (const float*)d_in[6];
  const float* Ur = (const float*)d_in[7];
  const float* br = (const float*)d_in[8];
  const float* Wh = (const float*)d_in[9];
  const float* Uh = (const float*)d_in[10];
  const float* bh = (const float*)d_in[11];
  unsigned short* wt = (unsigned short*)d_ws;   // 16 slabs x 48 KB = 768 KB

  wprep<<<1536, 256, 0, stream>>>(Wu, Wr, Wh, Uu, Ur, Uh, wt);

  const int lds_bytes = 163840;                 // 2x48K weights + 2x32K x/h
  hipFuncSetAttribute((const void*)augru_main,
                      hipFuncAttributeMaxDynamicSharedMemorySize, lds_bytes);

  const int rows = in_sizes[0] / 256;           // 65536
  augru_main<<<rows / 64, 512, lds_bytes, stream>>>(x, h1, a, wt, bu, br, bh,
                                                    (float*)d_out);
}

// Round 4
// 102.327 us; speedup vs baseline: 2.5342x; 1.0844x over previous
//
#include <hip/hip_runtime.h>

typedef __attribute__((ext_vector_type(8))) short short8;
typedef __attribute__((ext_vector_type(16))) float f32x16;

#define MFMA32 __builtin_amdgcn_mfma_f32_32x32x16_bf16

__device__ __forceinline__ unsigned short f2bf(float f) {
  unsigned int u = __float_as_uint(f);
  u += 0x7fffu + ((u >> 16) & 1u);
  return (unsigned short)(u >> 16);
}

__device__ __forceinline__ float bf2f(unsigned short s) {
  unsigned int u = ((unsigned int)s) << 16;
  return __uint_as_float(u);
}

// Pre-pack the 6 weight matrices fp32 [k][n] -> bf16 MFMA-fragment order:
// wt[(((s*6 + g)*8 + c)*64 + l)*8 + j] = G_g[k][n]
//   with k = s*16 + (l>>5)*8 + j, n = c*32 + (l&31)
// One (slab,gate,chunk) brick = 1 KB = one wave's B-fragment, contiguous.
__global__ __launch_bounds__(256) void wprep(
    const float* __restrict__ Wu, const float* __restrict__ Wr, const float* __restrict__ Wh,
    const float* __restrict__ Uu, const float* __restrict__ Ur, const float* __restrict__ Uh,
    unsigned short* __restrict__ wt) {
  int idx = blockIdx.x * 256 + threadIdx.x;   // 0 .. 6*65536-1
  int j = idx & 7;
  int l = (idx >> 3) & 63;
  int c = (idx >> 9) & 7;
  int sg = idx >> 12;
  int g = sg % 6;
  int s = sg / 6;
  int k = s * 16 + (l >> 5) * 8 + j;
  int n = c * 32 + (l & 31);
  const float* src = (g == 0) ? Wu : (g == 1) ? Wr : (g == 2) ? Wh
                   : (g == 3) ? Uu : (g == 4) ? Ur : Uh;
  wt[idx] = f2bf(src[k * 256 + n]);
}

// Fused AUGRU. Block = 512 thr (8 waves), tile 64 rows x 256 cols.
// Wave w owns cols [32w, 32w+32), all 64 rows, mfma 32x32x16.
// Weights: global -> VGPR direct (wave-private fragments), ring-prefetched,
// NO barriers in the K-loop. x-pass then h-pass; h tile staged during x-pass.
__global__ __launch_bounds__(512, 2) void augru_main(
    const float* __restrict__ x, const float* __restrict__ h1,
    const float* __restrict__ a, const unsigned short* __restrict__ wt,
    const float* __restrict__ bu, const float* __restrict__ br,
    const float* __restrict__ bh, float* __restrict__ out) {
  __shared__ char lX[32768];    // x tile bf16, swizzled
  __shared__ char lH[32768];    // h tile bf16, swizzled

  const int tid = threadIdx.x;
  const int l   = tid & 63;
  const int wid = tid >> 6;          // 0..7 -> 32-col chunk
  const int fr  = l & 31;            // row (A) / col (B,C)
  const int fq  = l >> 5;            // k-half (A/B) / row+4 group (C)
  const long rowbase = (long)blockIdx.x * 64;
  const int aswz = (fr & 7) << 4;

  const char* wb = (const char*)wt + (wid << 10) + (l << 4);
#define WOFF(SG) ((SG) << 13)

  // ---- prefetch weight fragments: slabs 0,1, gates 0-2 ----
  short8 wA0 = *(const short8*)(wb + WOFF(0 * 6 + 0));
  short8 wA1 = *(const short8*)(wb + WOFF(0 * 6 + 1));
  short8 wA2 = *(const short8*)(wb + WOFF(0 * 6 + 2));
  short8 wB0 = *(const short8*)(wb + WOFF(1 * 6 + 0));
  short8 wB1 = *(const short8*)(wb + WOFF(1 * 6 + 1));
  short8 wB2 = *(const short8*)(wb + WOFF(1 * 6 + 2));

  // ---- stage x tile (fp32 -> bf16, swizzled byte ^= (row&7)<<4) ----
  {
    const float* src = x + rowbase * 256;
#pragma unroll
    for (int i = 0; i < 8; ++i) {
      int f   = i * 512 + tid;
      int row = f >> 6;
      int kq  = f & 63;
      float4 v = ((const float4*)src)[f];
      ushort4 b;
      b.x = f2bf(v.x); b.y = f2bf(v.y); b.z = f2bf(v.z); b.w = f2bf(v.w);
      *(ushort4*)(lX + (row << 9) + ((kq * 8) ^ ((row & 7) << 4))) = b;
    }
  }
  // issue first half of h tile loads (landed mid x-pass)
  const float* hsrc = h1 + rowbase * 256;
  float4 h0_, h1_, h2_, h3_, h4_, h5_, h6_, h7_;
  h0_ = ((const float4*)hsrc)[0 * 512 + tid];
  h1_ = ((const float4*)hsrc)[1 * 512 + tid];
  h2_ = ((const float4*)hsrc)[2 * 512 + tid];
  h3_ = ((const float4*)hsrc)[3 * 512 + tid];

  __syncthreads();   // lX ready

#define HWRITE(V, I)                                                        \
  {                                                                         \
    int f = (I) * 512 + tid;                                                \
    int row = f >> 6;                                                       \
    int kq = f & 63;                                                        \
    ushort4 b;                                                              \
    b.x = f2bf(V.x); b.y = f2bf(V.y); b.z = f2bf(V.z); b.w = f2bf(V.w);     \
    *(ushort4*)(lH + (row << 9) + ((kq * 8) ^ ((row & 7) << 4))) = b;       \
  }

  f32x16 accU0 = {}, accU1 = {};
  f32x16 accR0 = {}, accR1 = {};
  f32x16 accXH0 = {}, accXH1 = {};
  f32x16 accHH0 = {}, accHH1 = {};

#define XSLAB(S, W0, W1, W2, PG)                                            \
  {                                                                         \
    const int koff = (((S) << 5) + (fq << 4)) ^ aswz;                       \
    short8 ax0 = *(const short8*)(lX + (fr << 9) + koff);                   \
    short8 ax1 = *(const short8*)(lX + ((fr + 32) << 9) + koff);            \
    accU0 = MFMA32(ax0, W0, accU0, 0, 0, 0);                                \
    accU1 = MFMA32(ax1, W0, accU1, 0, 0, 0);                                \
    W0 = *(const short8*)(wb + WOFF((PG) + 0));                             \
    accR0 = MFMA32(ax0, W1, accR0, 0, 0, 0);                                \
    accR1 = MFMA32(ax1, W1, accR1, 0, 0, 0);                                \
    W1 = *(const short8*)(wb + WOFF((PG) + 1));                             \
    accXH0 = MFMA32(ax0, W2, accXH0, 0, 0, 0);                              \
    accXH1 = MFMA32(ax1, W2, accXH1, 0, 0, 0);                              \
    W2 = *(const short8*)(wb + WOFF((PG) + 2));                             \
  }

#define HSLAB(S, W0, W1, W2, PG)                                            \
  {                                                                         \
    const int koff = (((S) << 5) + (fq << 4)) ^ aswz;                       \
    short8 ah0 = *(const short8*)(lH + (fr << 9) + koff);                   \
    short8 ah1 = *(const short8*)(lH + ((fr + 32) << 9) + koff);            \
    accU0 = MFMA32(ah0, W0, accU0, 0, 0, 0);                                \
    accU1 = MFMA32(ah1, W0, accU1, 0, 0, 0);                                \
    W0 = *(const short8*)(wb + WOFF((PG) + 0));                             \
    accR0 = MFMA32(ah0, W1, accR0, 0, 0, 0);                                \
    accR1 = MFMA32(ah1, W1, accR1, 0, 0, 0);                                \
    W1 = *(const short8*)(wb + WOFF((PG) + 1));                             \
    accHH0 = MFMA32(ah0, W2, accHH0, 0, 0, 0);                              \
    accHH1 = MFMA32(ah1, W2, accHH1, 0, 0, 0);                              \
    W2 = *(const short8*)(wb + WOFF((PG) + 2));                             \
  }

  // ---- x-pass: slabs 0..15, gates 0-2 (Wu,Wr,Wh). No barriers. ----
  for (int s = 0; s < 16; s += 2) {
    // prefetch index: 2 slabs ahead; last iters roll over to h-pass weights
    const int pg = (s + 2 < 16) ? (s + 2) * 6 : 3;        // slab0 gates 3-5
    const int qg = (s + 3 < 16) ? (s + 3) * 6 : 1 * 6 + 3; // slab1 gates 3-5
    XSLAB(s, wA0, wA1, wA2, pg)
    XSLAB(s + 1, wB0, wB1, wB2, qg)
    if (s == 6) {
      HWRITE(h0_, 0) HWRITE(h1_, 1) HWRITE(h2_, 2) HWRITE(h3_, 3)
      h4_ = ((const float4*)hsrc)[4 * 512 + tid];
      h5_ = ((const float4*)hsrc)[5 * 512 + tid];
      h6_ = ((const float4*)hsrc)[6 * 512 + tid];
      h7_ = ((const float4*)hsrc)[7 * 512 + tid];
    }
    if (s == 14) {
      HWRITE(h4_, 4) HWRITE(h5_, 5) HWRITE(h6_, 6) HWRITE(h7_, 7)
    }
  }
  __syncthreads();   // lH ready

  // ---- h-pass: slabs 0..15, gates 3-5 (Uu,Ur,Uh). No barriers. ----
  for (int s = 0; s < 16; s += 2) {
    const int pg = ((s + 2 < 16) ? (s + 2) : 15) * 6 + 3;
    const int qg = ((s + 3 < 16) ? (s + 3) : 15) * 6 + 3;
    HSLAB(s, wA0, wA1, wA2, pg)
    HSLAB(s + 1, wB0, wB1, wB2, qg)
  }

  // ---- epilogue: gates + blend; full-128B-line stores ----
  const int n = wid * 32 + fr;
  const float vbu = bu[n], vbr = br[n], vbh = bh[n];

#define EPI(ACCU, ACCR, ACCXH, ACCHH, MBASE)                                \
  _Pragma("unroll")                                                         \
  for (int g8 = 0; g8 < 4; ++g8) {                                          \
    _Pragma("unroll")                                                       \
    for (int j = 0; j < 4; ++j) {                                           \
      const int reg = g8 * 4 + j;                                           \
      const int rl  = (MBASE) + g8 * 8 + fq * 4 + j;                        \
      const long grow = rowbase + rl;                                       \
      const float av = a[grow];                                             \
      const float pu = ACCU[reg] + vbu;                                     \
      const float pr = ACCR[reg] + vbr;                                     \
      const float uu = 1.f / (1.f + __expf(-pu));                           \
      const float rr = 1.f / (1.f + __expf(-pr));                           \
      const float cc = ACCXH[reg] + rr * ACCHH[reg] + vbh;                  \
      const float th = 2.f / (1.f + __expf(-2.f * cc)) - 1.f;               \
      const float uh = av * uu;                                             \
      const int hb = (rl << 9) + ((((n >> 2) << 3)) ^ ((rl & 7) << 4)) + ((n & 3) << 1); \
      const float h1v = bf2f(*(const unsigned short*)(lH + hb));            \
      out[grow * 256 + n] = (1.f - uh) * h1v + uh * th;                     \
    }                                                                       \
  }

  EPI(accU0, accR0, accXH0, accHH0, 0)
  EPI(accU1, accR1, accXH1, accHH1, 32)
#undef EPI
#undef HSLAB
#undef XSLAB
#undef HWRITE
#undef WOFF
}

extern "C" void kernel_launch(void* const* d_in, const int* in_sizes, int n_in,
                              void* d_out, int out_size, void* d_ws, size_t ws_size,
                              hipStream_t stream) {
  const float* x  = (const float*)d_in[0];
  const float* h1 = (const float*)d_in[1];
  const float* a  = (const float*)d_in[2];
  const float* Wu = (const float*)d_in[3];
  const float* Uu = (const float*)d_in[4];
  const float* bu = (const float*)d_in[5];
  const float* Wr = (const float*)d_in[6];
  const float* Ur = (const float*)d_in[7];
  const float* br = (const float*)d_in[8];
  const float* Wh = (const float*)d_in[9];
  const float* Uh = (const float*)d_in[10];
  const float* bh = (const float*)d_in[11];
  unsigned short* wt = (unsigned short*)d_ws;   // 16 slabs x 48 KB = 768 KB

  wprep<<<1536, 256, 0, stream>>>(Wu, Wr, Wh, Uu, Ur, Uh, wt);

  const int rows = in_sizes[0] / 256;           // 65536
  augru_main<<<rows / 64, 512, 0, stream>>>(x, h1, a, wt, bu, br, bh,
                                            (float*)d_out);
}

// Round 5
// 92.050 us; speedup vs baseline: 2.8172x; 1.1116x over previous
//
#include <hip/hip_runtime.h>

typedef __attribute__((ext_vector_type(8))) short short8;
typedef __attribute__((ext_vector_type(16))) float f32x16;

#define MFMA32 __builtin_amdgcn_mfma_f32_32x32x16_bf16

__device__ __forceinline__ unsigned short f2bf(float f) {
  unsigned int u = __float_as_uint(f);
  u += 0x7fffu + ((u >> 16) & 1u);
  return (unsigned short)(u >> 16);
}

// Pre-pack the 6 weight matrices fp32 [k][n] -> bf16 MFMA-fragment order:
// wt[(((s*6 + g)*8 + c)*64 + l)*8 + j] = G_g[k][n]
//   with k = s*16 + (l>>5)*8 + j, n = c*32 + (l&31)
// One (slab,gate,chunk) brick = 1 KB = one wave's B-fragment, contiguous.
__global__ __launch_bounds__(256) void wprep(
    const float* __restrict__ Wu, const float* __restrict__ Wr, const float* __restrict__ Wh,
    const float* __restrict__ Uu, const float* __restrict__ Ur, const float* __restrict__ Uh,
    unsigned short* __restrict__ wt) {
  int idx = blockIdx.x * 256 + threadIdx.x;   // 0 .. 6*65536-1
  int j = idx & 7;
  int l = (idx >> 3) & 63;
  int c = (idx >> 9) & 7;
  int sg = idx >> 12;
  int g = sg % 6;
  int s = sg / 6;
  int k = s * 16 + (l >> 5) * 8 + j;
  int n = c * 32 + (l & 31);
  const float* src = (g == 0) ? Wu : (g == 1) ? Wr : (g == 2) ? Wh
                   : (g == 3) ? Uu : (g == 4) ? Ur : Uh;
  wt[idx] = f2bf(src[k * 256 + n]);
}

// Fused AUGRU. Block = 512 thr (8 waves), tile 64 rows x 256 cols.
// Wave w owns cols [32w, 32w+32), all 64 rows, mfma 32x32x16.
// Weights: global->VGPR ring, depth 4 slabs. No barriers in K-loops.
__global__ __launch_bounds__(512, 2) void augru_main(
    const float* __restrict__ x, const float* __restrict__ h1,
    const float* __restrict__ a, const unsigned short* __restrict__ wt,
    const float* __restrict__ bu, const float* __restrict__ br,
    const float* __restrict__ bh, float* __restrict__ out) {
  extern __shared__ char smem[];
  char* lX = smem;                       // 32768 B x tile bf16, swizzled
  char* lH = smem + 32768;               // 32768 B h tile bf16, swizzled
  float* a_s = (float*)(smem + 65536);   // 64 floats

  const int tid = threadIdx.x;
  const int l   = tid & 63;
  const int wid = tid >> 6;          // 0..7 -> 32-col chunk
  const int fr  = l & 31;            // row (A) / col (B,C)
  const int fq  = l >> 5;            // k-half (A/B) / row+4 group (C)
  const long rowbase = (long)blockIdx.x * 64;
  const int aswz = (fr & 7) << 4;
  const int n = wid * 32 + fr;

  const char* wb = (const char*)wt + (wid << 10) + (l << 4);
#define WOFF(SG) ((SG) << 13)

  // ---- issue x tile loads (all 8 up front: max MLP) ----
  const float* xsrc = x + rowbase * 256;
  float4 xv[8];
#pragma unroll
  for (int i = 0; i < 8; ++i) xv[i] = ((const float4*)xsrc)[i * 512 + tid];

  // ---- prefetch W ring: x-gate slabs 0..3 ----
  short8 W[4][3];
#pragma unroll
  for (int i = 0; i < 4; ++i)
#pragma unroll
    for (int g = 0; g < 3; ++g)
      W[i][g] = *(const short8*)(wb + WOFF(i * 6 + g));

  // ---- issue first half of h tile loads ----
  const float* hsrc = h1 + rowbase * 256;
  float4 hv[8];
#pragma unroll
  for (int i = 0; i < 4; ++i) hv[i] = ((const float4*)hsrc)[i * 512 + tid];

  const float vbu = bu[n], vbr = br[n], vbh = bh[n];
  if (tid < 64) a_s[tid] = a[rowbase + tid];

  // ---- convert + write x tile (swizzled: byte ^= (row&7)<<4) ----
#pragma unroll
  for (int i = 0; i < 8; ++i) {
    int f   = i * 512 + tid;
    int row = f >> 6;
    int kq  = f & 63;
    ushort4 b;
    b.x = f2bf(xv[i].x); b.y = f2bf(xv[i].y); b.z = f2bf(xv[i].z); b.w = f2bf(xv[i].w);
    *(ushort4*)(lX + (row << 9) + ((kq * 8) ^ ((row & 7) << 4))) = b;
  }
  __syncthreads();   // lX ready

#define HWRITE(I)                                                           \
  {                                                                         \
    int f = (I) * 512 + tid;                                                \
    int row = f >> 6;                                                       \
    int kq = f & 63;                                                        \
    ushort4 b;                                                              \
    b.x = f2bf(hv[I].x); b.y = f2bf(hv[I].y);                               \
    b.z = f2bf(hv[I].z); b.w = f2bf(hv[I].w);                               \
    *(ushort4*)(lH + (row << 9) + ((kq * 8) ^ ((row & 7) << 4))) = b;       \
  }

  f32x16 accU0 = {}, accU1 = {};
  f32x16 accR0 = {}, accR1 = {};
  f32x16 accXH0 = {}, accXH1 = {};
  f32x16 accHH0 = {}, accHH1 = {};

  // ---- x-pass: slabs 0..15, gates 0-2 (Wu,Wr,Wh). No barriers. ----
#pragma unroll
  for (int s = 0; s < 16; ++s) {
    const int koff = ((s << 5) + (fq << 4)) ^ aswz;
    short8 ax0 = *(const short8*)(lX + (fr << 9) + koff);
    short8 ax1 = *(const short8*)(lX + ((fr + 32) << 9) + koff);
    __builtin_amdgcn_s_setprio(1);
    accU0  = MFMA32(ax0, W[s & 3][0], accU0, 0, 0, 0);
    accU1  = MFMA32(ax1, W[s & 3][0], accU1, 0, 0, 0);
    accR0  = MFMA32(ax0, W[s & 3][1], accR0, 0, 0, 0);
    accR1  = MFMA32(ax1, W[s & 3][1], accR1, 0, 0, 0);
    accXH0 = MFMA32(ax0, W[s & 3][2], accXH0, 0, 0, 0);
    accXH1 = MFMA32(ax1, W[s & 3][2], accXH1, 0, 0, 0);
    __builtin_amdgcn_s_setprio(0);
    // refill ring set (s&3): 4 slabs ahead; roll into h-gate slabs 0..3
    const int sg = (s + 4 < 16) ? (s + 4) * 6 : (s - 12) * 6 + 3;
#pragma unroll
    for (int g = 0; g < 3; ++g)
      W[s & 3][g] = *(const short8*)(wb + WOFF(sg + g));
    if (s == 4) {
#pragma unroll
      for (int i = 4; i < 8; ++i) hv[i] = ((const float4*)hsrc)[i * 512 + tid];
    }
    if (s == 8)  { HWRITE(0) HWRITE(1) HWRITE(2) HWRITE(3) }
    if (s == 12) { HWRITE(4) HWRITE(5) HWRITE(6) HWRITE(7) }
  }
  __syncthreads();   // lH ready

  // ---- h-pass: slabs 0..15, gates 3-5 (Uu,Ur,Uh). No barriers. ----
#pragma unroll
  for (int s = 0; s < 16; ++s) {
    const int koff = ((s << 5) + (fq << 4)) ^ aswz;
    short8 ah0 = *(const short8*)(lH + (fr << 9) + koff);
    short8 ah1 = *(const short8*)(lH + ((fr + 32) << 9) + koff);
    __builtin_amdgcn_s_setprio(1);
    accU0  = MFMA32(ah0, W[s & 3][0], accU0, 0, 0, 0);
    accU1  = MFMA32(ah1, W[s & 3][0], accU1, 0, 0, 0);
    accR0  = MFMA32(ah0, W[s & 3][1], accR0, 0, 0, 0);
    accR1  = MFMA32(ah1, W[s & 3][1], accR1, 0, 0, 0);
    accHH0 = MFMA32(ah0, W[s & 3][2], accHH0, 0, 0, 0);
    accHH1 = MFMA32(ah1, W[s & 3][2], accHH1, 0, 0, 0);
    __builtin_amdgcn_s_setprio(0);
    if (s + 4 < 16) {
      const int sg = (s + 4) * 6 + 3;
#pragma unroll
      for (int g = 0; g < 3; ++g)
        W[s & 3][g] = *(const short8*)(wb + WOFF(sg + g));
    }
  }

  // ---- epilogue: coalesced fp32 h1 re-read (L2/L3-hot), light gate math ----
  const float* hcol = h1 + rowbase * 256 + n;
  float* ocol = out + rowbase * 256 + n;
  float hE0[16], hE1[16];
#pragma unroll
  for (int g8 = 0; g8 < 4; ++g8)
#pragma unroll
    for (int j = 0; j < 4; ++j) {
      const int rl = g8 * 8 + fq * 4 + j;
      hE0[g8 * 4 + j] = hcol[(long)rl * 256];
      hE1[g8 * 4 + j] = hcol[(long)(rl + 32) * 256];
    }

#define EPI(ACCU, ACCR, ACCXH, ACCHH, HE, RB)                               \
  _Pragma("unroll")                                                         \
  for (int g8 = 0; g8 < 4; ++g8) {                                          \
    _Pragma("unroll")                                                       \
    for (int j = 0; j < 4; ++j) {                                           \
      const int reg = g8 * 4 + j;                                           \
      const int rl  = (RB) + g8 * 8 + fq * 4 + j;                           \
      const float pu = ACCU[reg] + vbu;                                     \
      const float pr = ACCR[reg] + vbr;                                     \
      const float uu = __builtin_amdgcn_rcpf(1.f + __expf(-pu));            \
      const float rr = __builtin_amdgcn_rcpf(1.f + __expf(-pr));            \
      const float cc = fmaf(rr, ACCHH[reg], ACCXH[reg]) + vbh;              \
      const float tt = __builtin_amdgcn_rcpf(1.f + __expf(-2.f * cc));      \
      const float th = fmaf(2.f, tt, -1.f);                                 \
      const float uh = a_s[rl] * uu;                                        \
      const float h1v = HE[reg];                                            \
      ocol[(long)rl * 256] = fmaf(uh, th - h1v, h1v);                       \
    }                                                                       \
  }

  EPI(accU0, accR0, accXH0, accHH0, hE0, 0)
  EPI(accU1, accR1, accXH1, accHH1, hE1, 32)
#undef EPI
#undef HWRITE
#undef WOFF
}

extern "C" void kernel_launch(void* const* d_in, const int* in_sizes, int n_in,
                              void* d_out, int out_size, void* d_ws, size_t ws_size,
                              hipStream_t stream) {
  const float* x  = (const float*)d_in[0];
  const float* h1 = (const float*)d_in[1];
  const float* a  = (const float*)d_in[2];
  const float* Wu = (const float*)d_in[3];
  const float* Uu = (const float*)d_in[4];
  const float* bu = (const float*)d_in[5];
  const float* Wr = (const float*)d_in[6];
  const float* Ur = (const float*)d_in[7];
  const float* br = (const float*)d_in[8];
  const float* Wh = (const float*)d_in[9];
  const float* Uh = (const float*)d_in[10];
  const float* bh = (const float*)d_in[11];
  unsigned short* wt = (unsigned short*)d_ws;   // 16 slabs x 48 KB = 768 KB

  wprep<<<1536, 256, 0, stream>>>(Wu, Wr, Wh, Uu, Ur, Uh, wt);

  const int lds_bytes = 65536 + 256;
  hipFuncSetAttribute((const void*)augru_main,
                      hipFuncAttributeMaxDynamicSharedMemorySize, lds_bytes);

  const int rows = in_sizes[0] / 256;           // 65536
  augru_main<<<rows / 64, 512, lds_bytes, stream>>>(x, h1, a, wt, bu, br, bh,
                                                    (float*)d_out);
}